// Round 1
// baseline (2238.823 us; speedup 1.0000x reference)
//
#include <hip/hip_runtime.h>
#include <hip/hip_bf16.h>
#include <math.h>

// Problem dims
#define BB 8
#define TT 16
#define HH 112
#define WW 112
#define CC 3
#define FF 16
#define HP 56
#define WP 56
#define HO 54
#define WO 54
#define NC 6

// ws layout (floats)
#define POOLED_ELEMS (128*56*56*16)   // 6,422,528
#define HSTATE_ELEMS (8*54*54*16)     // 373,248

__device__ __forceinline__ float hsig(float x) {
    return fminf(fmaxf(0.2f*x + 0.5f, 0.0f), 1.0f);
}

// Kernel 1: fused 7x7 SAME conv (3->16) + bias + relu + 2x2 maxpool.
// One thread per pooled output pixel; 16 filters in registers.
// Weight indices are wave-uniform -> scalar loads on the SMEM pipe.
__global__ __launch_bounds__(256) void conv_pool_kernel(
    const float* __restrict__ x,      // [128,112,112,3]
    const float* __restrict__ cw,     // [7,7,3,16]
    const float* __restrict__ cb,     // [16]
    float* __restrict__ pooled)       // [128,56,56,16]
{
    int idx = blockIdx.x * 256 + threadIdx.x;   // 128*56*56 = 401408 = 1568*256 exact
    int fr = idx / (HP*WP);
    int r  = idx % (HP*WP);
    int ph = r / WP, pw = r % WP;

    const float* xf = x + (size_t)fr * HH * WW * CC;

    float best[16];
    #pragma unroll
    for (int i = 0; i < 16; ++i) best[i] = -1e30f;

    for (int py = 0; py < 2; ++py) {
        for (int px = 0; px < 2; ++px) {
            int oh = 2*ph + py, ow = 2*pw + px;
            float acc[16];
            #pragma unroll
            for (int i = 0; i < 16; ++i) acc[i] = cb[i];
            for (int ky = 0; ky < 7; ++ky) {
                int ih = oh - 3 + ky;
                if (ih < 0 || ih >= HH) continue;
                for (int kx = 0; kx < 7; ++kx) {
                    int iw = ow - 3 + kx;
                    if (iw < 0 || iw >= WW) continue;
                    const float* xp = xf + ((size_t)ih * WW + iw) * CC;
                    const float* wp = cw + ((ky*7 + kx) * CC) * 16;
                    #pragma unroll
                    for (int ci = 0; ci < 3; ++ci) {
                        float a = xp[ci];
                        #pragma unroll
                        for (int fo = 0; fo < 16; ++fo)
                            acc[fo] += a * wp[ci*16 + fo];
                    }
                }
            }
            #pragma unroll
            for (int i = 0; i < 16; ++i) best[i] = fmaxf(best[i], acc[i]);
        }
    }

    float4* op = (float4*)(pooled + (size_t)idx * 16);
    #pragma unroll
    for (int v = 0; v < 4; ++v) {
        float4 o;
        o.x = fmaxf(best[v*4+0], 0.0f);
        o.y = fmaxf(best[v*4+1], 0.0f);
        o.z = fmaxf(best[v*4+2], 0.0f);
        o.w = fmaxf(best[v*4+3], 0.0f);
        op[v] = o;
    }
}

// Kernel 2: one ConvLSTM time step, fully fused:
//   zx = conv3x3 VALID (pooled frame, 16->64)  [recomputed, not staged]
//   zh = conv3x3 SAME  (h_in, 16->64)
//   gates + state update, writes h_out and c in place.
// Thread = one output pixel x 4 feature channels (all 4 gates) -> 16 accs.
// Channel group comes from blockIdx.y so weight addresses are wave-uniform.
__global__ __launch_bounds__(256) void lstm_step_kernel(
    const float* __restrict__ pooled,   // [128,56,56,16]
    const float* __restrict__ h_in,     // [8,54,54,16]
    float* __restrict__ h_out,          // [8,54,54,16]
    float* __restrict__ cst,            // [8,54,54,16]
    const float* __restrict__ wk,       // [3,3,16,64]
    const float* __restrict__ wr,       // [3,3,16,64]
    const float* __restrict__ bias,     // [64]
    int t)
{
    const int NPIX = BB * HO * WO;  // 23328
    int pix = blockIdx.x * 256 + threadIdx.x;
    if (pix >= NPIX) return;
    int cg = blockIdx.y;            // 0..3 : feature channels cg*4 .. cg*4+3

    int b  = pix / (HO*WO);
    int r  = pix % (HO*WO);
    int oh = r / WO, ow = r % WO;

    float acc[16];                  // [gate][j]
    #pragma unroll
    for (int i = 0; i < 16; ++i) acc[i] = 0.0f;

    const float* pf = pooled + (size_t)(b*TT + t) * HP * WP * 16;
    const float* hb = h_in + (size_t)b * HO * WO * 16;

    for (int ky = 0; ky < 3; ++ky) {
        int ph = oh + ky;           // VALID: 0..55, always in range
        int hy = oh + ky - 1;       // SAME pad for recurrent conv
        for (int kx = 0; kx < 3; ++kx) {
            int pw = ow + kx;
            int hx = ow + kx - 1;
            bool hv = (hy >= 0 && hy < HO && hx >= 0 && hx < WO);
            const float* pp  = pf + ((size_t)ph * WP + pw) * 16;
            const float* hp  = hb + ((size_t)hy * WO + hx) * 16;
            const float* wkp = wk + ((ky*3 + kx) * 16) * 64 + cg*4;
            const float* wrp = wr + ((ky*3 + kx) * 16) * 64 + cg*4;
            #pragma unroll
            for (int ci = 0; ci < 16; ++ci) {
                float a = pp[ci];
                float h = hv ? hp[ci] : 0.0f;
                #pragma unroll
                for (int g = 0; g < 4; ++g) {
                    #pragma unroll
                    for (int j = 0; j < 4; ++j) {
                        acc[g*4 + j] += a * wkp[ci*64 + g*16 + j]
                                      + h * wrp[ci*64 + g*16 + j];
                    }
                }
            }
        }
    }

    size_t base = (((size_t)b * HO + oh) * WO + ow) * 16 + cg*4;
    float4 hnew;
    float* hn = &hnew.x;
    #pragma unroll
    for (int j = 0; j < 4; ++j) {
        float iv = hsig(acc[0*4 + j] + bias[0*16 + cg*4 + j]);
        float fv = hsig(acc[1*4 + j] + bias[1*16 + cg*4 + j]);
        float gv = tanhf(acc[2*4 + j] + bias[2*16 + cg*4 + j]);
        float ov = hsig(acc[3*4 + j] + bias[3*16 + cg*4 + j]);
        float cold = cst[base + j];
        float cn = fv * cold + iv * gv;
        cst[base + j] = cn;
        hn[j] = ov * tanhf(cn);
    }
    *(float4*)(h_out + base) = hnew;
}

// Kernel 3: spatial mean over 54x54 -> dense(16->6) -> softmax. One block per b.
__global__ __launch_bounds__(256) void head_kernel(
    const float* __restrict__ h,    // [8,54,54,16]
    const float* __restrict__ dw,   // [16,6]
    const float* __restrict__ db,   // [6]
    float* __restrict__ out)        // [8,6]
{
    int b = blockIdx.x;
    int tid = threadIdx.x;
    const float* hb = h + (size_t)b * HO * WO * 16;
    float s = 0.0f;
    for (int i = tid; i < HO*WO*16; i += 256) s += hb[i];  // stride 256 == 0 mod 16 -> fixed ch per thread
    __shared__ float red[256];
    red[tid] = s;
    __syncthreads();
    for (int st = 128; st >= 16; st >>= 1) {
        if (tid < st) red[tid] += red[tid + st];
        __syncthreads();
    }
    __shared__ float logits[8];
    if (tid < NC) {
        float l = db[tid];
        #pragma unroll
        for (int ch = 0; ch < 16; ++ch)
            l += (red[ch] * (1.0f/2916.0f)) * dw[ch*NC + tid];
        logits[tid] = l;
    }
    __syncthreads();
    if (tid < NC) {
        float m = -1e30f;
        for (int k = 0; k < NC; ++k) m = fmaxf(m, logits[k]);
        float e = expf(logits[tid] - m);
        float d = 0.0f;
        for (int k = 0; k < NC; ++k) d += expf(logits[k] - m);
        out[b*NC + tid] = e / d;
    }
}

extern "C" void kernel_launch(void* const* d_in, const int* in_sizes, int n_in,
                              void* d_out, int out_size, void* d_ws, size_t ws_size,
                              hipStream_t stream) {
    const float* x      = (const float*)d_in[0];
    const float* conv_w = (const float*)d_in[1];
    const float* conv_b = (const float*)d_in[2];
    const float* wk     = (const float*)d_in[3];
    const float* wr     = (const float*)d_in[4];
    const float* bias   = (const float*)d_in[5];
    const float* dw     = (const float*)d_in[6];
    const float* db     = (const float*)d_in[7];
    float* out = (float*)d_out;

    float* ws     = (float*)d_ws;
    float* pooled = ws;
    float* hA     = pooled + POOLED_ELEMS;
    float* hB     = hA + HSTATE_ELEMS;
    float* cbuf   = hB + HSTATE_ELEMS;

    // h0 = 0, c0 = 0 (ws is poisoned before every launch)
    hipMemsetAsync(hA,   0, HSTATE_ELEMS * sizeof(float), stream);
    hipMemsetAsync(cbuf, 0, HSTATE_ELEMS * sizeof(float), stream);

    conv_pool_kernel<<<dim3(1568), dim3(256), 0, stream>>>(x, conv_w, conv_b, pooled);

    for (int t = 0; t < TT; ++t) {
        const float* hin = (t & 1) ? hB : hA;
        float*       hout = (t & 1) ? hA : hB;
        lstm_step_kernel<<<dim3(92, 4), dim3(256), 0, stream>>>(
            pooled, hin, hout, cbuf, wk, wr, bias, t);
    }
    // t=15 (odd) wrote hA
    head_kernel<<<dim3(8), dim3(256), 0, stream>>>(hA, dw, db, out);
}

// Round 2
// 2194.175 us; speedup vs baseline: 1.0203x; 1.0203x over previous
//
#include <hip/hip_runtime.h>
#include <hip/hip_bf16.h>
#include <math.h>

// Problem dims
#define BB 8
#define TT 16
#define HH 112
#define WW 112
#define CC 3
#define FF 16
#define HP 56
#define WP 56
#define HO 54
#define WO 54
#define NC 6

// ws layout (floats)
#define POOLED_ELEMS (128*56*56*16)   // 6,422,528
#define HSTATE_ELEMS (8*54*54*16)     // 373,248
#define NPIX (BB*HO*WO)               // 23328

__device__ __forceinline__ float hsig(float x) {
    return fminf(fmaxf(0.2f*x + 0.5f, 0.0f), 1.0f);
}

// Kernel 1: fused 7x7 SAME conv (3->16) + bias + relu + 2x2 maxpool.
// One thread per pooled output pixel; 16 filters in registers.
__global__ __launch_bounds__(256) void conv_pool_kernel(
    const float* __restrict__ x,      // [128,112,112,3]
    const float* __restrict__ cw,     // [7,7,3,16]
    const float* __restrict__ cb,     // [16]
    float* __restrict__ pooled)       // [128,56,56,16]
{
    int idx = blockIdx.x * 256 + threadIdx.x;   // 128*56*56 = 401408 = 1568*256 exact
    int fr = idx / (HP*WP);
    int r  = idx % (HP*WP);
    int ph = r / WP, pw = r % WP;

    const float* xf = x + (size_t)fr * HH * WW * CC;

    float best[16];
    #pragma unroll
    for (int i = 0; i < 16; ++i) best[i] = -1e30f;

    for (int py = 0; py < 2; ++py) {
        for (int px = 0; px < 2; ++px) {
            int oh = 2*ph + py, ow = 2*pw + px;
            float acc[16];
            #pragma unroll
            for (int i = 0; i < 16; ++i) acc[i] = cb[i];
            for (int ky = 0; ky < 7; ++ky) {
                int ih = oh - 3 + ky;
                if (ih < 0 || ih >= HH) continue;
                for (int kx = 0; kx < 7; ++kx) {
                    int iw = ow - 3 + kx;
                    if (iw < 0 || iw >= WW) continue;
                    const float* xp = xf + ((size_t)ih * WW + iw) * CC;
                    const float* wp = cw + ((ky*7 + kx) * CC) * 16;
                    #pragma unroll
                    for (int ci = 0; ci < 3; ++ci) {
                        float a = xp[ci];
                        #pragma unroll
                        for (int fo = 0; fo < 16; ++fo)
                            acc[fo] += a * wp[ci*16 + fo];
                    }
                }
            }
            #pragma unroll
            for (int i = 0; i < 16; ++i) best[i] = fmaxf(best[i], acc[i]);
        }
    }

    float4* op = (float4*)(pooled + (size_t)idx * 16);
    #pragma unroll
    for (int v = 0; v < 4; ++v) {
        float4 o;
        o.x = fmaxf(best[v*4+0], 0.0f);
        o.y = fmaxf(best[v*4+1], 0.0f);
        o.z = fmaxf(best[v*4+2], 0.0f);
        o.w = fmaxf(best[v*4+3], 0.0f);
        op[v] = o;
    }
}

// Kernel 2: one ConvLSTM time step, fully fused.
// Thread = one output pixel x ONE feature channel (4 gate accumulators).
// blockIdx.y = channel -> weight addresses stay wave-uniform (s_load).
// Grid: 92 x 16 = 1472 blocks -> ~5.7 blocks/CU, ~23 waves/CU.
__global__ __launch_bounds__(256) void lstm_step_kernel(
    const float* __restrict__ pooled,   // [128,56,56,16]
    const float* __restrict__ h_in,     // [8,54,54,16]
    float* __restrict__ h_out,          // [8,54,54,16]
    float* __restrict__ cst,            // [8,54,54,16]
    const float* __restrict__ wk,       // [3,3,16,64]
    const float* __restrict__ wr,       // [3,3,16,64]
    const float* __restrict__ bias,     // [64]
    int t)
{
    int pix = blockIdx.x * 256 + threadIdx.x;
    if (pix >= NPIX) return;
    int ch = blockIdx.y;            // 0..15 feature channel (wave-uniform)

    int b  = pix / (HO*WO);
    int r  = pix % (HO*WO);
    int oh = r / WO, ow = r % WO;

    float acc0 = 0.f, acc1 = 0.f, acc2 = 0.f, acc3 = 0.f;

    const float* pf = pooled + (size_t)(b*TT + t) * HP * WP * 16;
    const float* hb = h_in + (size_t)b * HO * WO * 16;

    for (int ky = 0; ky < 3; ++ky) {
        int ph = oh + ky;           // VALID: always in range 0..55
        int hy = oh + ky - 1;       // SAME pad for recurrent conv
        for (int kx = 0; kx < 3; ++kx) {
            int pw = ow + kx;
            int hx = ow + kx - 1;
            bool hv = (hy >= 0 && hy < HO && hx >= 0 && hx < WO);

            const float4* pp = (const float4*)(pf + ((size_t)ph * WP + pw) * 16);
            const float4* hp = (const float4*)(hb + ((size_t)hy * WO + hx) * 16);

            float a[16], h[16];
            #pragma unroll
            for (int v = 0; v < 4; ++v) {
                float4 av = pp[v];
                a[v*4+0] = av.x; a[v*4+1] = av.y; a[v*4+2] = av.z; a[v*4+3] = av.w;
                float4 hv4 = hv ? hp[v] : make_float4(0.f, 0.f, 0.f, 0.f);
                h[v*4+0] = hv4.x; h[v*4+1] = hv4.y; h[v*4+2] = hv4.z; h[v*4+3] = hv4.w;
            }

            const float* wkp = wk + ((ky*3 + kx) * 16) * 64 + ch;  // [ci*64 + gate*16 + ch]
            const float* wrp = wr + ((ky*3 + kx) * 16) * 64 + ch;
            #pragma unroll
            for (int ci = 0; ci < 16; ++ci) {
                float av = a[ci], hvv = h[ci];
                acc0 += av * wkp[ci*64 +  0] + hvv * wrp[ci*64 +  0];
                acc1 += av * wkp[ci*64 + 16] + hvv * wrp[ci*64 + 16];
                acc2 += av * wkp[ci*64 + 32] + hvv * wrp[ci*64 + 32];
                acc3 += av * wkp[ci*64 + 48] + hvv * wrp[ci*64 + 48];
            }
        }
    }

    float iv = hsig(acc0 + bias[ 0 + ch]);
    float fv = hsig(acc1 + bias[16 + ch]);
    float gv = tanhf(acc2 + bias[32 + ch]);
    float ov = hsig(acc3 + bias[48 + ch]);

    size_t base = (size_t)pix * 16 + ch;
    float cold = cst[base];
    float cn = fv * cold + iv * gv;
    cst[base] = cn;
    h_out[base] = ov * tanhf(cn);
}

// Kernel 3: spatial mean over 54x54 -> dense(16->6) -> softmax. One block per b.
__global__ __launch_bounds__(256) void head_kernel(
    const float* __restrict__ h,    // [8,54,54,16]
    const float* __restrict__ dw,   // [16,6]
    const float* __restrict__ db,   // [6]
    float* __restrict__ out)        // [8,6]
{
    int b = blockIdx.x;
    int tid = threadIdx.x;
    const float* hb = h + (size_t)b * HO * WO * 16;
    float s = 0.0f;
    for (int i = tid; i < HO*WO*16; i += 256) s += hb[i];  // stride 256 == 0 mod 16 -> fixed ch per thread
    __shared__ float red[256];
    red[tid] = s;
    __syncthreads();
    for (int st = 128; st >= 16; st >>= 1) {
        if (tid < st) red[tid] += red[tid + st];
        __syncthreads();
    }
    __shared__ float logits[8];
    if (tid < NC) {
        float l = db[tid];
        #pragma unroll
        for (int ch = 0; ch < 16; ++ch)
            l += (red[ch] * (1.0f/2916.0f)) * dw[ch*NC + tid];
        logits[tid] = l;
    }
    __syncthreads();
    if (tid < NC) {
        float m = -1e30f;
        for (int k = 0; k < NC; ++k) m = fmaxf(m, logits[k]);
        float e = expf(logits[tid] - m);
        float d = 0.0f;
        for (int k = 0; k < NC; ++k) d += expf(logits[k] - m);
        out[b*NC + tid] = e / d;
    }
}

extern "C" void kernel_launch(void* const* d_in, const int* in_sizes, int n_in,
                              void* d_out, int out_size, void* d_ws, size_t ws_size,
                              hipStream_t stream) {
    const float* x      = (const float*)d_in[0];
    const float* conv_w = (const float*)d_in[1];
    const float* conv_b = (const float*)d_in[2];
    const float* wk     = (const float*)d_in[3];
    const float* wr     = (const float*)d_in[4];
    const float* bias   = (const float*)d_in[5];
    const float* dw     = (const float*)d_in[6];
    const float* db     = (const float*)d_in[7];
    float* out = (float*)d_out;

    float* ws     = (float*)d_ws;
    float* pooled = ws;
    float* hA     = pooled + POOLED_ELEMS;
    float* hB     = hA + HSTATE_ELEMS;
    float* cbuf   = hB + HSTATE_ELEMS;

    // h0 = 0, c0 = 0 (ws is poisoned before every launch)
    hipMemsetAsync(hA,   0, HSTATE_ELEMS * sizeof(float), stream);
    hipMemsetAsync(cbuf, 0, HSTATE_ELEMS * sizeof(float), stream);

    conv_pool_kernel<<<dim3(1568), dim3(256), 0, stream>>>(x, conv_w, conv_b, pooled);

    for (int t = 0; t < TT; ++t) {
        const float* hin  = (t & 1) ? hB : hA;
        float*       hout = (t & 1) ? hA : hB;
        lstm_step_kernel<<<dim3(92, 16), dim3(256), 0, stream>>>(
            pooled, hin, hout, cbuf, wk, wr, bias, t);
    }
    // t=15 (odd) wrote hA
    head_kernel<<<dim3(8), dim3(256), 0, stream>>>(hA, dw, db, out);
}